// Round 17
// baseline (8167.369 us; speedup 1.0000x reference)
//
#include <hip/hip_runtime.h>

typedef unsigned short ushort_t;

// ---- problem constants ----
constexpr int kB   = 32;
constexpr int kL   = 12;
constexpr int kN   = 325;
constexpr int kNP  = 328;          // padded node count
constexpr int kPc  = kB * kNP;     // 10496 column stride, channel-major
constexpr int kHID = 64;
constexpr int kDIN = 198;          // 3 * 66
constexpr int kND  = 40;
constexpr int kNN2 = kN * kN;
constexpr float cAW = 0.05f, cBW = 0.95f, cGW = 0.95f, cTA = 3.0f;

constexpr int kT = 192;            // threads for generic kernels (3 waves)
constexpr int kWs = 384;           // transposed-E w rows (6 strips x 64)
constexpr int kVs = 352;           // transposed-E v stride (11*32, padded)
constexpr int kETb = kWs * kVs;    // per-b elements = 135168

constexpr int kBldEV  = 1152;      // 6 wblk * 6 vblk * 32 b
constexpr int kPairs  = 231;       // 21*22/2 unordered 16-tile pairs

// combined-gate MFMA weights: K padded to 352 (= 66 + 4*66 = 330 real)
constexpr int kKg  = 352;
constexpr int kWgN = 2 * 128 * kKg;   // enc/dec x (z,r) x K
constexpr int kWfN = 2 * 64 * kKg;    // enc/dec x Cn x K

// init index-space regions
constexpr int kInit1 = 66 * kPc;                    // xH
constexpr int kInit2 = 2 * kND * kN;                // e1T/e2T
constexpr int kInit3 = 2 * kETb;                    // a0T/a1T hi/lo/f (transposed)
constexpr int kInit4 = 4 * kB * kETb / 2;           // zero E block as uints
constexpr int kInit5 = 12 * kDIN * kHID;            // rnwC combos
constexpr int kInit6 = 8 * kDIN * 16;               // hw1C combos
constexpr int kInit7 = 2 * kETb;                    // a0N/a1N (normal orientation)
constexpr int kInit8 = 4 * kPc * 64 / 2;            // zero nv hi/lo block as uints
constexpr int kInitT = kInit1 + kInit2 + kInit3 + kInit4 + kInit5 + kInit6 + kInit7 + kInit8;

using short8 = __attribute__((ext_vector_type(8))) short;
using f32x4  = __attribute__((ext_vector_type(4))) float;
union ABu { ushort_t u[8]; short8 v; };

__device__ __forceinline__ float sigm_f(float x) { return 1.f / (1.f + __expf(-x)); }
__device__ __forceinline__ float tanh_f(float x) { return 1.f - 2.f / (1.f + __expf(2.f * x)); }
__device__ __forceinline__ ushort_t f2b(float x) {   // fp32 -> bf16 RNE
    union { float f; unsigned u; } c; c.f = x;
    unsigned r = c.u + 0x7FFFu + ((c.u >> 16) & 1u);
    return (ushort_t)(r >> 16);
}
__device__ __forceinline__ float b2f(ushort_t h) {
    union { unsigned u; float f; } c; c.u = ((unsigned)h) << 16; return c.f;
}
__device__ __forceinline__ void split_bf(float x, ushort_t& hi, ushort_t& lo) {
    hi = f2b(x);
    lo = f2b(x - b2f(hi));
}

struct KParams {
    const float *hist, *fut, *adj0, *adj1, *emb1, *emb2;
    const float *hw1, *hb1, *hw2, *hb2, *hw3, *hb3, *rnw, *rnb, *fcw, *fcb;
    float* out;
    float *xH, *tmp;                                      // fp32 state buffers
    ushort_t *h1Ah, *h1Al, *h1Bh, *h1Bl;                  // hop1 outputs, hi/lo [c][kPc]
    ushort_t *h2Ah, *h2Al, *h2Bh, *h2Bl;                  // hop2 outputs, hi/lo [c][kPc]
    float *zbuf, *e1T, *e2T, *rs, *cs, *adjv;
    float *a0Tf, *a1Tf;                                   // fp32 transposed adj [w][v]
    float *rnwC, *hw1C;                                   // combined weights
    ushort_t *E0h, *E0l, *E1h, *E1l;                      // bf16 hi/lo E^T [b][w][v]
    ushort_t *a0h, *a0l, *a1h, *a1l;                      // bf16 hi/lo adj^T [w][v]
    ushort_t *a0Nh, *a0Nl, *a1Nh, *a1Nl;                  // bf16 hi/lo adj (normal) [v][u]
    ushort_t *a0sh, *a0sl, *a1sh, *a1sl;                  // bf16 hi/lo (adj^2)^T [w][v]
    ushort_t *Wgh, *Wgl, *Wfh, *Wfl;                      // gate/final MFMA weights
    ushort_t *nv1h, *nv1l, *nv2h, *nv2l;                  // bf16 hi/lo nv [p][64]
};

// ---------------------------------------------------------------------------
__device__ __forceinline__ void d_init(const KParams& P, int i) {
    if (i < kInit1) {
        int c = i / kPc, p = i - c * kPc;
        int b = p / kNP, n = p - b * kNP;
        if (n < kN) {
            float v = (c < 2) ? P.hist[((b * kL) * kN + n) * 2 + c] : 0.f;
            P.xH[(size_t)c * kPc + p] = v;
        }
        return;
    }
    int j = i - kInit1;
    if (j < kND * kN) { int d = j / kN, n = j - d * kN; P.e1T[j] = P.emb1[n * kND + d]; return; }
    j -= kND * kN;
    if (j < kND * kN) { int d = j / kN, n = j - d * kN; P.e2T[j] = P.emb2[n * kND + d]; return; }
    j -= kND * kN;
    if (j < kInit3) {   // transposed copies: aT[w][v] = adj[v][w]
        int m = j / kETb, idx = j - m * kETb;
        int w = idx / kVs, v = idx - w * kVs;
        const float* adj = m ? P.adj1 : P.adj0;
        float val = (w < kN && v < kN) ? adj[(size_t)v * kN + w] : 0.f;
        ushort_t hi, lo; split_bf(val, hi, lo);
        if (m) { P.a1h[idx] = hi; P.a1l[idx] = lo; P.a1Tf[idx] = val; }
        else   { P.a0h[idx] = hi; P.a0l[idx] = lo; P.a0Tf[idx] = val; }
        return;
    }
    j -= kInit3;
    if (j < kInit4) { ((unsigned*)P.E0h)[j] = 0; return; }   // E0h..E1l contiguous
    j -= kInit4;
    if (j < kInit5) {
        int m = j / (kDIN * kHID), rem = j - m * (kDIN * kHID);
        int k = rem / kHID, o = rem - k * kHID;
        const float* W = P.rnw + (size_t)m * (kDIN * kHID) + o;
        float v;
        if (k < 66)        v = W[(size_t)k * kHID] + cAW * (W[(size_t)(k + 66) * kHID] + W[(size_t)(k + 132) * kHID]);
        else if (k < 132)  v = W[(size_t)k * kHID] + cAW * W[(size_t)(k + 66) * kHID];
        else               v = W[(size_t)k * kHID];
        P.rnwC[j] = v;
        return;
    }
    j -= kInit5;
    if (j < kInit6) {
        int m = j / (kDIN * 16), rem = j - m * (kDIN * 16);
        int k = rem / 16, o = rem - k * 16;
        const float* W = P.hw1 + (size_t)m * (kDIN * 16) + o;
        float v;
        if (k < 66)        v = W[(size_t)k * 16] + cAW * (W[(size_t)(k + 66) * 16] + W[(size_t)(k + 132) * 16]);
        else if (k < 132)  v = cGW * (W[(size_t)k * 16] + cAW * W[(size_t)(k + 66) * 16]);
        else               v = cGW * cGW * W[(size_t)k * 16];
        P.hw1C[j] = v;
        return;
    }
    j -= kInit6;
    if (j < kInit7) {   // normal-orientation copies: aN[v][u] = adj[v][u]
        int m = j / kETb, idx = j - m * kETb;
        int v = idx / kVs, u = idx - v * kVs;
        const float* adj = m ? P.adj1 : P.adj0;
        float val = (v < kN && u < kN) ? adj[(size_t)v * kN + u] : 0.f;
        ushort_t hi, lo; split_bf(val, hi, lo);
        if (m) { P.a1Nh[idx] = hi; P.a1Nl[idx] = lo; }
        else   { P.a0Nh[idx] = hi; P.a0Nl[idx] = lo; }
        return;
    }
    j -= kInit7;
    if (j < kInit8) ((unsigned*)P.nv1h)[j] = 0;   // nv1h..nv2l contiguous
}
__global__ __launch_bounds__(kT) void g_init(KParams P) {
    const int gtid = blockIdx.x * kT + threadIdx.x;
    const int nt = gridDim.x * kT;
    for (int i = gtid; i < kInitT; i += nt) d_init(P, i);
}

// ---------------------------------------------------------------------------
// g_init2: build gate/final MFMA weight fragments from rnwC.
__global__ __launch_bounds__(kT) void g_init2(KParams P) {
    const int tot = kWgN + kWfN;
    for (int i = blockIdx.x * kT + threadIdx.x; i < tot; i += gridDim.x * kT) {
        bool isG = i < kWgN;
        int j = isG ? i : i - kWgN;
        int Mloc = isG ? 128 : 64;
        int g = j / (Mloc * kKg);
        int rem = j - g * (Mloc * kKg);
        int m = rem / kKg, k = rem - m * kKg;
        int rbg = g ? 6 : 0;
        int base0, base1, h;
        if (isG) {
            if (m < 64) { base0 = rbg + 0; base1 = rbg + 1; h = m; }
            else        { base0 = rbg + 2; base1 = rbg + 3; h = m - 64; }
        } else { base0 = rbg + 4; base1 = rbg + 5; h = m; }
        float w = 0.f;
        if (k < 66)
            w = P.rnwC[(size_t)base0 * (kDIN * kHID) + k * kHID + h]
              + P.rnwC[(size_t)base1 * (kDIN * kHID) + k * kHID + h];
        else if (k < 198)
            w = P.rnwC[(size_t)base0 * (kDIN * kHID) + k * kHID + h];
        else if (k < 330)
            w = P.rnwC[(size_t)base1 * (kDIN * kHID) + (k - 132) * kHID + h];
        ushort_t hi, lo; split_bf(w, hi, lo);
        if (isG) { P.Wgh[j] = hi; P.Wgl[j] = lo; }
        else     { P.Wfh[j] = hi; P.Wfl[j] = lo; }
    }
}

// ---------------------------------------------------------------------------
// g_esq: (adj^2)^T = aT * aN (split-bf16 3-mfma).  Once per call.
__global__ __launch_bounds__(64) void g_esq(KParams P) {
    const int lane = threadIdx.x;
    const int quad = lane >> 4, ln15 = lane & 15;
    const int m0 = blockIdx.x * 16, n0 = blockIdx.y * 16;
    const int mat = blockIdx.z;
    const ushort_t* STh = mat ? P.a1h : P.a0h;
    const ushort_t* STl = mat ? P.a1l : P.a0l;
    const ushort_t* SNh = mat ? P.a1Nh : P.a0Nh;
    const ushort_t* SNl = mat ? P.a1Nl : P.a0Nl;
    ushort_t* Oh = mat ? P.a1sh : P.a0sh;
    ushort_t* Ol = mat ? P.a1sl : P.a0sl;
    const size_t arow = (size_t)(m0 + ln15) * kVs + quad * 8;
    const size_t browq = (size_t)(n0 + ln15) * kVs + quad * 8;
    f32x4 acc = f32x4{0.f, 0.f, 0.f, 0.f};
    for (int ks = 0; ks < 11; ++ks) {
        const int u0 = ks * 32;
        ABu ah, al, bh, bl;
        ah.v = *(const short8*)(STh + arow + u0);
        al.v = *(const short8*)(STl + arow + u0);
        bh.v = *(const short8*)(SNh + browq + u0);
        bl.v = *(const short8*)(SNl + browq + u0);
        acc = __builtin_amdgcn_mfma_f32_16x16x32_bf16(ah.v, bh.v, acc, 0, 0, 0);
        acc = __builtin_amdgcn_mfma_f32_16x16x32_bf16(al.v, bh.v, acc, 0, 0, 0);
        acc = __builtin_amdgcn_mfma_f32_16x16x32_bf16(ah.v, bl.v, acc, 0, 0, 0);
    }
#pragma unroll
    for (int r = 0; r < 4; ++r) {
        size_t o = (size_t)(m0 + quad * 4 + r) * kVs + n0 + ln15;
        ushort_t hi, lo; split_bf(acc[r], hi, lo);
        Oh[o] = hi; Ol[o] = lo;
    }
}

// ---------------------------------------------------------------------------
// hop tile with fp32 A-source (converted on the fly), split-bf16 3-mfma.
__device__ __forceinline__ void hop_tile_f32(
        const ushort_t* __restrict__ EH, const ushort_t* __restrict__ EL,
        const float* __restrict__ ap, const size_t* brow, f32x4* acc) {
    for (int ks = 0; ks < 11; ++ks) {
        const int v0 = ks * 32;
        float4 f0 = *(const float4*)(ap + v0);
        float4 f1 = *(const float4*)(ap + v0 + 4);
        float fs[8] = {f0.x, f0.y, f0.z, f0.w, f1.x, f1.y, f1.z, f1.w};
        ABu ah, al;
#pragma unroll
        for (int j = 0; j < 8; ++j) {
            ushort_t hi = f2b(fs[j]);
            ah.u[j] = hi;
            al.u[j] = f2b(fs[j] - b2f(hi));
        }
#pragma unroll
        for (int nn = 0; nn < 4; ++nn) {
            short8 bh = *(const short8*)(EH + brow[nn] + v0);
            short8 bl = *(const short8*)(EL + brow[nn] + v0);
            acc[nn] = __builtin_amdgcn_mfma_f32_16x16x32_bf16(ah.v, bh, acc[nn], 0, 0, 0);
            acc[nn] = __builtin_amdgcn_mfma_f32_16x16x32_bf16(al.v, bh, acc[nn], 0, 0, 0);
            acc[nn] = __builtin_amdgcn_mfma_f32_16x16x32_bf16(ah.v, bl, acc[nn], 0, 0, 0);
        }
    }
}

// hop tile with hi/lo bf16 A-source (direct 16B loads, no conversion).
__device__ __forceinline__ void hop_tile_hl(
        const ushort_t* __restrict__ EH, const ushort_t* __restrict__ EL,
        const ushort_t* __restrict__ aph, const ushort_t* __restrict__ apl,
        const size_t* brow, f32x4* acc) {
    for (int ks = 0; ks < 11; ++ks) {
        const int v0 = ks * 32;
        short8 ah = *(const short8*)(aph + v0);
        short8 al = *(const short8*)(apl + v0);
#pragma unroll
        for (int nn = 0; nn < 4; ++nn) {
            short8 bh = *(const short8*)(EH + brow[nn] + v0);
            short8 bl = *(const short8*)(EL + brow[nn] + v0);
            acc[nn] = __builtin_amdgcn_mfma_f32_16x16x32_bf16(ah, bh, acc[nn], 0, 0, 0);
            acc[nn] = __builtin_amdgcn_mfma_f32_16x16x32_bf16(al, bh, acc[nn], 0, 0, 0);
            acc[nn] = __builtin_amdgcn_mfma_f32_16x16x32_bf16(ah, bl, acc[nn], 0, 0, 0);
        }
    }
}

// ---------------------------------------------------------------------------
// g_hyper: both hyper hops in one launch (A and precomputed A^2, static).
// Outputs written as hi/lo bf16 pairs.
__global__ __launch_bounds__(320) void g_hyper(KParams P) {
    const int lane = threadIdx.x & 63;
    const int ct = threadIdx.x >> 6;
    const int quad = lane >> 4, ln15 = lane & 15;
    const int w0 = blockIdx.x * 64;
    const int zb = blockIdx.y;
    const int hop = zb >> 6;
    const int z = zb & 63;
    const int sel = z >> 5, b = z & 31;
    const ushort_t* EH = hop ? (sel ? P.a1sh : P.a0sh) : (sel ? P.a1h : P.a0h);
    const ushort_t* EL = hop ? (sel ? P.a1sl : P.a0sl) : (sel ? P.a1l : P.a0l);
    ushort_t* oh = (hop ? (sel ? P.h2Bh : P.h2Ah) : (sel ? P.h1Bh : P.h1Ah)) + b * kNP;
    ushort_t* ol = (hop ? (sel ? P.h2Bl : P.h2Al) : (sel ? P.h1Bl : P.h1Al)) + b * kNP;
    const float* ap = P.xH + b * kNP + (size_t)(ct * 16 + ln15) * kPc + quad * 8;
    size_t brow[4];
#pragma unroll
    for (int nn = 0; nn < 4; ++nn)
        brow[nn] = (size_t)(w0 + nn * 16 + ln15) * kVs + quad * 8;
    f32x4 acc[4];
#pragma unroll
    for (int nn = 0; nn < 4; ++nn) acc[nn] = f32x4{0.f, 0.f, 0.f, 0.f};
    hop_tile_f32(EH, EL, ap, brow, acc);
#pragma unroll
    for (int nn = 0; nn < 4; ++nn) {
        int w = w0 + nn * 16 + ln15;
        if (w < kN) {
#pragma unroll
            for (int r = 0; r < 4; ++r) {
                int c = ct * 16 + quad * 4 + r;
                if (c < 66) {
                    ushort_t hi, lo; split_bf(acc[nn][r], hi, lo);
                    oh[(size_t)c * kPc + w] = hi;
                    ol[(size_t)c * kPc + w] = lo;
                }
            }
        }
    }
}

// ---------------------------------------------------------------------------
// g_hop1: first RNN hop, fp32 src (xH or tmp) -> h1 hi/lo pairs.
__global__ __launch_bounds__(320) void g_hop1(KParams P, const float* __restrict__ src) {
    const int lane = threadIdx.x & 63;
    const int ct = threadIdx.x >> 6;
    const int quad = lane >> 4, ln15 = lane & 15;
    const int w0 = blockIdx.x * 64;
    const int zb = blockIdx.y;
    const int sel = zb >> 5, b = zb & 31;
    const ushort_t* EH = (sel ? P.E1h : P.E0h) + (size_t)b * kETb;
    const ushort_t* EL = (sel ? P.E1l : P.E0l) + (size_t)b * kETb;
    ushort_t* oh = (sel ? P.h1Bh : P.h1Ah) + b * kNP;
    ushort_t* ol = (sel ? P.h1Bl : P.h1Al) + b * kNP;
    const float* ap = src + b * kNP + (size_t)(ct * 16 + ln15) * kPc + quad * 8;
    size_t brow[4];
#pragma unroll
    for (int nn = 0; nn < 4; ++nn)
        brow[nn] = (size_t)(w0 + nn * 16 + ln15) * kVs + quad * 8;
    f32x4 acc[4];
#pragma unroll
    for (int nn = 0; nn < 4; ++nn) acc[nn] = f32x4{0.f, 0.f, 0.f, 0.f};
    hop_tile_f32(EH, EL, ap, brow, acc);
#pragma unroll
    for (int nn = 0; nn < 4; ++nn) {
        int w = w0 + nn * 16 + ln15;
        if (w < kN) {
#pragma unroll
            for (int r = 0; r < 4; ++r) {
                int c = ct * 16 + quad * 4 + r;
                if (c < 66) {
                    ushort_t hi, lo; split_bf(acc[nn][r], hi, lo);
                    oh[(size_t)c * kPc + w] = hi;
                    ol[(size_t)c * kPc + w] = lo;
                }
            }
        }
    }
}

// g_hop2: second RNN hop, hi/lo src (h1 pairs) -> h2 hi/lo pairs.  No A conversion.
__global__ __launch_bounds__(320) void g_hop2(KParams P) {
    const int lane = threadIdx.x & 63;
    const int ct = threadIdx.x >> 6;
    const int quad = lane >> 4, ln15 = lane & 15;
    const int w0 = blockIdx.x * 64;
    const int zb = blockIdx.y;
    const int sel = zb >> 5, b = zb & 31;
    const ushort_t* EH = (sel ? P.E1h : P.E0h) + (size_t)b * kETb;
    const ushort_t* EL = (sel ? P.E1l : P.E0l) + (size_t)b * kETb;
    const ushort_t* aph = (sel ? P.h1Bh : P.h1Ah) + b * kNP + (size_t)(ct * 16 + ln15) * kPc + quad * 8;
    const ushort_t* apl = (sel ? P.h1Bl : P.h1Al) + b * kNP + (size_t)(ct * 16 + ln15) * kPc + quad * 8;
    ushort_t* oh = (sel ? P.h2Bh : P.h2Ah) + b * kNP;
    ushort_t* ol = (sel ? P.h2Bl : P.h2Al) + b * kNP;
    size_t brow[4];
#pragma unroll
    for (int nn = 0; nn < 4; ++nn)
        brow[nn] = (size_t)(w0 + nn * 16 + ln15) * kVs + quad * 8;
    f32x4 acc[4];
#pragma unroll
    for (int nn = 0; nn < 4; ++nn) acc[nn] = f32x4{0.f, 0.f, 0.f, 0.f};
    hop_tile_hl(EH, EL, aph, apl, brow, acc);
#pragma unroll
    for (int nn = 0; nn < 4; ++nn) {
        int w = w0 + nn * 16 + ln15;
        if (w < kN) {
#pragma unroll
            for (int r = 0; r < 4; ++r) {
                int c = ct * 16 + quad * 4 + r;
                if (c < 66) {
                    ushort_t hi, lo; split_bf(acc[nn][r], hi, lo);
                    oh[(size_t)c * kPc + w] = hi;
                    ol[(size_t)c * kPc + w] = lo;
                }
            }
        }
    }
}

// ---------------------------------------------------------------------------
// g_gatesm: MFMA gates GEMM; staging: seg0 (xH fp32) split, segs 1-4 direct hi/lo copy.
__global__ __launch_bounds__(512) void g_gatesm(KParams P, int g, int rb) {
    __shared__ ushort_t Bh[2][32][40];
    __shared__ ushort_t Bl[2][32][40];
    const int t = threadIdx.x;
    const int lane = t & 63;
    const int wv = t >> 6;
    const int quad = lane >> 4, ln15 = lane & 15;
    const int p0 = blockIdx.x * 32;
    const ushort_t* segH[4] = {P.h1Ah, P.h2Ah, P.h1Bh, P.h2Bh};
    const ushort_t* segL[4] = {P.h1Al, P.h2Al, P.h1Bl, P.h2Bl};
    const int m = wv * 16 + ln15;
    const ushort_t* Ah = P.Wgh + ((size_t)(g * 128 + m)) * kKg + quad * 8;
    const ushort_t* Al = P.Wgl + ((size_t)(g * 128 + m)) * kKg + quad * 8;

    f32x4 acc[2];
    acc[0] = f32x4{0.f, 0.f, 0.f, 0.f};
    acc[1] = f32x4{0.f, 0.f, 0.f, 0.f};

    auto stage = [&](int bi, int ks) {
#pragma unroll
        for (int e = 0; e < 2; ++e) {
            int idx = e * 512 + t;
            int k = idx >> 5, n = idx & 31;
            int kg = ks * 32 + k;
            ushort_t hi = 0, lo = 0;
            if (kg < 66) {
                float v = P.xH[(size_t)kg * kPc + p0 + n];
                split_bf(v, hi, lo);
            } else if (kg < 330) {
                int seg = (kg - 66) / 66, row = (kg - 66) - seg * 66;
                size_t o = (size_t)row * kPc + p0 + n;
                hi = segH[seg][o];
                lo = segL[seg][o];
            }
            Bh[bi][n][k] = hi; Bl[bi][n][k] = lo;
        }
    };
    stage(0, 0);
    __syncthreads();
    for (int ks = 0; ks < 11; ++ks) {
        const int bi = ks & 1;
        ABu ah, al;
        ah.v = *(const short8*)(Ah + ks * 32);
        al.v = *(const short8*)(Al + ks * 32);
#pragma unroll
        for (int nt = 0; nt < 2; ++nt) {
            ABu bh, bl;
            bh.v = *(const short8*)&Bh[bi][nt * 16 + ln15][quad * 8];
            bl.v = *(const short8*)&Bl[bi][nt * 16 + ln15][quad * 8];
            acc[nt] = __builtin_amdgcn_mfma_f32_16x16x32_bf16(ah.v, bh.v, acc[nt], 0, 0, 0);
            acc[nt] = __builtin_amdgcn_mfma_f32_16x16x32_bf16(al.v, bh.v, acc[nt], 0, 0, 0);
            acc[nt] = __builtin_amdgcn_mfma_f32_16x16x32_bf16(ah.v, bl.v, acc[nt], 0, 0, 0);
        }
        if (ks + 1 < 11) stage((ks + 1) & 1, ks + 1);
        __syncthreads();
    }
#pragma unroll
    for (int nt = 0; nt < 2; ++nt) {
        int p = p0 + nt * 16 + ln15;
#pragma unroll
        for (int r = 0; r < 4; ++r) {
            int mm = wv * 16 + quad * 4 + r;
            float v = acc[nt][r];
            if (mm < 64) {
                int h = mm;
                float bz = P.rnb[(rb + 0) * kHID + h] + P.rnb[(rb + 1) * kHID + h];
                P.zbuf[(size_t)h * kPc + p] = sigm_f(v + bz);
            } else {
                int h = mm - 64;
                float br = P.rnb[(rb + 2) * kHID + h] + P.rnb[(rb + 3) * kHID + h];
                float rr = sigm_f(v + br);
                P.tmp[(size_t)(2 + h) * kPc + p] = rr * P.xH[(size_t)(2 + h) * kPc + p];
            }
        }
    }
    if (wv == 0 && quad == 0) {
#pragma unroll
        for (int nt = 0; nt < 2; ++nt) {
            int p = p0 + nt * 16 + ln15;
            P.tmp[p] = P.xH[p];
            P.tmp[kPc + p] = P.xH[kPc + p];
        }
    }
}

// ---------------------------------------------------------------------------
// g_finalm: MFMA Cn GEMM + GRU update + next-step x rows + folded decoder out.
__global__ __launch_bounds__(256) void g_finalm(KParams P, int g, int rb, int t_, int nextmode) {
    __shared__ ushort_t Bh[2][32][40];
    __shared__ ushort_t Bl[2][32][40];
    __shared__ float sred[16][33];
    const int t = threadIdx.x;
    const int lane = t & 63;
    const int wv = t >> 6;
    const int quad = lane >> 4, ln15 = lane & 15;
    const int p0 = blockIdx.x * 32;
    const ushort_t* segH[4] = {P.h1Ah, P.h2Ah, P.h1Bh, P.h2Bh};
    const ushort_t* segL[4] = {P.h1Al, P.h2Al, P.h1Bl, P.h2Bl};
    const int m = wv * 16 + ln15;
    const ushort_t* Ah = P.Wfh + ((size_t)(g * 64 + m)) * kKg + quad * 8;
    const ushort_t* Al = P.Wfl + ((size_t)(g * 64 + m)) * kKg + quad * 8;

    f32x4 acc[2];
    acc[0] = f32x4{0.f, 0.f, 0.f, 0.f};
    acc[1] = f32x4{0.f, 0.f, 0.f, 0.f};

    auto stage = [&](int bi, int ks) {
#pragma unroll
        for (int e = 0; e < 4; ++e) {
            int idx = e * 256 + t;
            int k = idx >> 5, n = idx & 31;
            int kg = ks * 32 + k;
            ushort_t hi = 0, lo = 0;
            if (kg < 66) {
                float v = P.tmp[(size_t)kg * kPc + p0 + n];
                split_bf(v, hi, lo);
            } else if (kg < 330) {
                int seg = (kg - 66) / 66, row = (kg - 66) - seg * 66;
                size_t o = (size_t)row * kPc + p0 + n;
                hi = segH[seg][o];
                lo = segL[seg][o];
            }
            Bh[bi][n][k] = hi; Bl[bi][n][k] = lo;
        }
    };
    stage(0, 0);
    __syncthreads();
    for (int ks = 0; ks < 11; ++ks) {
        const int bi = ks & 1;
        ABu ah, al;
        ah.v = *(const short8*)(Ah + ks * 32);
        al.v = *(const short8*)(Al + ks * 32);
#pragma unroll
        for (int nt = 0; nt < 2; ++nt) {
            ABu bh, bl;
            bh.v = *(const short8*)&Bh[bi][nt * 16 + ln15][quad * 8];
            bl.v = *(const short8*)&Bl[bi][nt * 16 + ln15][quad * 8];
            acc[nt] = __builtin_amdgcn_mfma_f32_16x16x32_bf16(ah.v, bh.v, acc[nt], 0, 0, 0);
            acc[nt] = __builtin_amdgcn_mfma_f32_16x16x32_bf16(al.v, bh.v, acc[nt], 0, 0, 0);
            acc[nt] = __builtin_amdgcn_mfma_f32_16x16x32_bf16(ah.v, bl.v, acc[nt], 0, 0, 0);
        }
        if (ks + 1 < 11) stage((ks + 1) & 1, ks + 1);
        __syncthreads();
    }
    float pout[2] = {0.f, 0.f};
#pragma unroll
    for (int nt = 0; nt < 2; ++nt) {
        int p = p0 + nt * 16 + ln15;
#pragma unroll
        for (int r = 0; r < 4; ++r) {
            int h = wv * 16 + quad * 4 + r;
            float bc = P.rnb[(rb + 4) * kHID + h] + P.rnb[(rb + 5) * kHID + h];
            float cn = tanh_f(acc[nt][r] + bc);
            float zz = P.zbuf[(size_t)h * kPc + p];
            size_t hidx = (size_t)(2 + h) * kPc + p;
            float hv = P.xH[hidx];
            float hn = zz * hv + (1.f - zz) * cn;
            P.xH[hidx] = hn;
            pout[nt] = fmaf(P.fcw[h], hn, pout[nt]);
        }
    }
    if (nextmode != 2) {
        if (wv == 0 && quad == 0) {
#pragma unroll
            for (int nt = 0; nt < 2; ++nt) {
                int p = p0 + nt * 16 + ln15;
                int b = p / kNP, n = p - b * kNP;
                if (n < kN) {
                    float r0, r1;
                    if (nextmode == 0) {
                        r0 = P.hist[((b * kL + (t_ + 1)) * kN + n) * 2 + 0];
                        r1 = P.hist[((b * kL + (t_ + 1)) * kN + n) * 2 + 1];
                    } else {
                        r0 = 0.f;
                        r1 = P.fut[((b * kL + 0) * kN + n) * 2 + 1];
                    }
                    P.xH[p] = r0;
                    P.xH[kPc + p] = r1;
                }
            }
        }
    } else {
#pragma unroll
        for (int nt = 0; nt < 2; ++nt)
            sred[wv * 4 + quad][nt * 16 + ln15] = pout[nt];
        __syncthreads();
        if (t < 32) {
            int col = t;
            float s = P.fcb[0];
#pragma unroll
            for (int q = 0; q < 16; ++q) s += sred[q][col];
            int p = p0 + col;
            int b = p / kNP, n = p - b * kNP;
            if (n < kN) {
                P.out[(b * 12 + t_) * kN + n] = s;
                if (t_ + 1 < 12) {
                    P.xH[p] = s;
                    P.xH[kPc + p] = P.fut[((b * kL + (t_ + 1)) * kN + n) * 2 + 1];
                }
            }
        }
    }
}

// ---------------------------------------------------------------------------
// fused hyper MLP (combined hw1C); hyper inputs read as hi+lo; nv out hi/lo.
__global__ __launch_bounds__(768) void g_mlp(KParams P, int hy0) {
    {
        int zt = blockIdx.x * 768 + threadIdx.x;
        if (zt < kB * kN) P.rs[zt] = 0.f;
        else if (zt < 2 * kB * kN) P.cs[zt - kB * kN] = 0.f;
    }
    __shared__ float part[12][16][64];
    __shared__ float s2s[4][2][64];
    const int lane = threadIdx.x & 63;
    const int wv = threadIdx.x >> 6;
    const int p = blockIdx.x * 64 + lane;
    const int m = wv & 3, s = wv >> 2;
    const int ig = hy0 + m;
    const ushort_t* srcH = (s == 1) ? ((m & 1) ? P.h1Bh : P.h1Ah)
                                    : ((m & 1) ? P.h2Bh : P.h2Ah);
    const ushort_t* srcL = (s == 1) ? ((m & 1) ? P.h1Bl : P.h1Al)
                                    : ((m & 1) ? P.h2Bl : P.h2Al);
    const float* wp = P.hw1C + (size_t)ig * (kDIN * 16);
    float acc[16];
#pragma unroll
    for (int o = 0; o < 16; ++o) acc[o] = 0.f;
#pragma unroll 2
    for (int kl = 0; kl < 66; ++kl) {
        int kk = s * 66 + kl;
        float u;
        if (s == 0) u = P.xH[(size_t)kl * kPc + p];
        else {
            size_t o = (size_t)kl * kPc + p;
            u = b2f(srcH[o]) + b2f(srcL[o]);
        }
        float4 wa = *(const float4*)(wp + kk * 16);
        float4 wb = *(const float4*)(wp + kk * 16 + 4);
        float4 wc = *(const float4*)(wp + kk * 16 + 8);
        float4 wd = *(const float4*)(wp + kk * 16 + 12);
        acc[0]  = fmaf(u, wa.x, acc[0]);  acc[1]  = fmaf(u, wa.y, acc[1]);
        acc[2]  = fmaf(u, wa.z, acc[2]);  acc[3]  = fmaf(u, wa.w, acc[3]);
        acc[4]  = fmaf(u, wb.x, acc[4]);  acc[5]  = fmaf(u, wb.y, acc[5]);
        acc[6]  = fmaf(u, wb.z, acc[6]);  acc[7]  = fmaf(u, wb.w, acc[7]);
        acc[8]  = fmaf(u, wc.x, acc[8]);  acc[9]  = fmaf(u, wc.y, acc[9]);
        acc[10] = fmaf(u, wc.z, acc[10]); acc[11] = fmaf(u, wc.w, acc[11]);
        acc[12] = fmaf(u, wd.x, acc[12]); acc[13] = fmaf(u, wd.y, acc[13]);
        acc[14] = fmaf(u, wd.z, acc[14]); acc[15] = fmaf(u, wd.w, acc[15]);
    }
#pragma unroll
    for (int o = 0; o < 16; ++o) part[wv][o][lane] = acc[o];
    __syncthreads();
    if (wv < 4) {
        int mm = wv, igm = hy0 + mm;
        float sv[16];
#pragma unroll
        for (int o = 0; o < 16; ++o)
            sv[o] = sigm_f(P.hb1[igm * 16 + o] + part[mm][o][lane] + part[4 + mm][o][lane] + part[8 + mm][o][lane]);
#pragma unroll
        for (int j = 0; j < 2; ++j) {
            float t = P.hb2[igm * 2 + j];
#pragma unroll
            for (int o = 0; o < 16; ++o) t = fmaf(sv[o], P.hw2[igm * 32 + o * 2 + j], t);
            s2s[mm][j][lane] = sigm_f(t);
        }
    }
    __syncthreads();
    int b = p / kNP, n = p - b * kNP;
    int nc = (n < kN) ? n : (kN - 1);
    bool ok = (n < kN);
    if (wv < 2) {
        int i0 = hy0 + wv * 2;
        float sa0 = s2s[wv * 2 + 0][0][lane], sa1 = s2s[wv * 2 + 0][1][lane];
        float sb0 = s2s[wv * 2 + 1][0][lane], sb1 = s2s[wv * 2 + 1][1][lane];
        const float* eT = wv ? P.e2T : P.e1T;
        ushort_t* nvh = wv ? P.nv2h : P.nv1h;
        ushort_t* nvl = wv ? P.nv2l : P.nv1l;
#pragma unroll 4
        for (int d = 0; d < kND; ++d) {
            float f = P.hb3[(i0 + 0) * kND + d] + P.hb3[(i0 + 1) * kND + d]
                    + sa0 * P.hw3[(i0 + 0) * 80 + d] + sa1 * P.hw3[(i0 + 0) * 80 + 40 + d]
                    + sb0 * P.hw3[(i0 + 1) * 80 + d] + sb1 * P.hw3[(i0 + 1) * 80 + 40 + d];
            float r = tanh_f(cTA * eT[d * kN + nc] * f);
            if (ok) {
                ushort_t hi, lo; split_bf(r, hi, lo);
                nvh[(size_t)p * 64 + d] = hi;
                nvl[(size_t)p * 64 + d] = lo;
            }
        }
    }
}

// ---------------------------------------------------------------------------
// g_adjm: MFMA adjacency (R14-proven).
__global__ __launch_bounds__(64) void g_adjm(KParams P) {
    __shared__ float c2t[16][17];
    const int b = blockIdx.y;
    int ti = 0, rem = blockIdx.x;
    while (rem >= 21 - ti) { rem -= 21 - ti; ++ti; }
    const int tj = ti + rem;
    const int i0 = ti * 16, j0 = tj * 16;
    const int lane = threadIdx.x, quad = lane >> 4, ln15 = lane & 15;
    const size_t pb = (size_t)b * kNP;
    auto rowoff = [&](int n) {
        int ncl = (n < kNP) ? n : (kNP - 1);
        return (pb + ncl) * 64 + quad * 8;
    };
    const size_t aI = rowoff(i0 + ln15);
    const size_t aJ = rowoff(j0 + ln15);

    f32x4 c1 = f32x4{0.f, 0.f, 0.f, 0.f};
    f32x4 c2 = f32x4{0.f, 0.f, 0.f, 0.f};
#pragma unroll
    for (int ks = 0; ks < 2; ++ks) {
        const int k0 = ks * 32;
        ABu a1h, a1l, b1h, b1l, a2h, a2l, b2h, b2l;
        a1h.v = *(const short8*)(P.nv1h + aI + k0);
        a1l.v = *(const short8*)(P.nv1l + aI + k0);
        b1h.v = *(const short8*)(P.nv2h + aJ + k0);
        b1l.v = *(const short8*)(P.nv2l + aJ + k0);
        c1 = __builtin_amdgcn_mfma_f32_16x16x32_bf16(a1h.v, b1h.v, c1, 0, 0, 0);
        c1 = __builtin_amdgcn_mfma_f32_16x16x32_bf16(a1l.v, b1h.v, c1, 0, 0, 0);
        c1 = __builtin_amdgcn_mfma_f32_16x16x32_bf16(a1h.v, b1l.v, c1, 0, 0, 0);
        a2h.v = *(const short8*)(P.nv1h + aJ + k0);
        a2l.v = *(const short8*)(P.nv1l + aJ + k0);
        b2h.v = *(const short8*)(P.nv2h + aI + k0);
        b2l.v = *(const short8*)(P.nv2l + aI + k0);
        c2 = __builtin_amdgcn_mfma_f32_16x16x32_bf16(a2h.v, b2h.v, c2, 0, 0, 0);
        c2 = __builtin_amdgcn_mfma_f32_16x16x32_bf16(a2l.v, b2h.v, c2, 0, 0, 0);
        c2 = __builtin_amdgcn_mfma_f32_16x16x32_bf16(a2h.v, b2l.v, c2, 0, 0, 0);
    }
#pragma unroll
    for (int r = 0; r < 4; ++r) c2t[quad * 4 + r][ln15] = c2[r];
    __syncthreads();

    size_t base = (size_t)b * kNN2;
    const bool diag = (ti == tj);
    float v1[4], v2[4];
#pragma unroll
    for (int r = 0; r < 4; ++r) {
        int i = i0 + quad * 4 + r;
        int j = j0 + ln15;
        float aji = c2t[ln15][quad * 4 + r];
        float tv = tanh_f(cTA * (c1[r] - aji));
        bool valid = (i < kN) && (j < kN);
        v1[r] = valid ? fmaxf(tv, 0.f) : 0.f;
        v2[r] = valid ? fmaxf(-tv, 0.f) : 0.f;
        if (valid) {
            P.adjv[base + (size_t)i * kN + j] = v1[r];
            if (!diag) P.adjv[base + (size_t)j * kN + i] = v2[r];
        }
    }
#pragma unroll
    for (int r = 0; r < 4; ++r) {
        float sr = v1[r];
#pragma unroll
        for (int off = 1; off < 16; off <<= 1) sr += __shfl_xor(sr, off);
        int i = i0 + quad * 4 + r;
        if (ln15 == 0 && i < kN) atomicAdd(&P.rs[b * kN + i], sr);
    }
    {
        float pc = v1[0] + v1[1] + v1[2] + v1[3];
        pc += __shfl_xor(pc, 16);
        pc += __shfl_xor(pc, 32);
        int j = j0 + ln15;
        if (quad == 0 && j < kN) atomicAdd(&P.cs[b * kN + j], pc);
    }
    if (!diag) {
        {
            float pr = v2[0] + v2[1] + v2[2] + v2[3];
            pr += __shfl_xor(pr, 16);
            pr += __shfl_xor(pr, 32);
            int j = j0 + ln15;
            if (quad == 0 && j < kN) atomicAdd(&P.rs[b * kN + j], pr);
        }
#pragma unroll
        for (int r = 0; r < 4; ++r) {
            float sc = v2[r];
#pragma unroll
            for (int off = 1; off < 16; off <<= 1) sc += __shfl_xor(sc, off);
            int i = i0 + quad * 4 + r;
            if (ln15 == 0 && i < kN) atomicAdd(&P.cs[b * kN + i], sc);
        }
    }
}

// ---------------------------------------------------------------------------
// buildE: transposed bf16 hi/lo E0/E1 — R14-proven
__global__ __launch_bounds__(kT) void g_buildE(KParams P) {
    __shared__ float tA[64][65];
    __shared__ float tB[64][65];
    for (int vb = blockIdx.x; vb < kBldEV; vb += gridDim.x) {
        const int lane = threadIdx.x & 63;
        const int wv = threadIdx.x >> 6;
        const int w0 = (vb % 6) * 64;
        const int v0 = ((vb / 6) % 6) * 64;
        const int b = vb / 36;
        const float* av = P.adjv + (size_t)b * kNN2;
        for (int r = wv; r < 64; r += 3) {
            int v = v0 + r, w = w0 + lane;
            tA[r][lane] = (v < kN && w < kN) ? av[(size_t)v * kN + w] : 0.f;
            int v2 = w0 + r, w2 = v0 + lane;
            tB[r][lane] = (v2 < kN && w2 < kN) ? av[(size_t)v2 * kN + w2] : 0.f;
        }
        __syncthreads();
        for (int r = wv; r < 64; r += 3) {
            int w = w0 + r;
            int v = v0 + lane;
            if (w < kN && v < kN) {
                size_t o = ((size_t)b * kWs + w) * kVs + v;
                float dlt = (v == w) ? 1.f : 0.f;
                {
                    float iv = 1.f / (1.f + P.rs[b * kN + v]);
                    float e = cBW * (tA[lane][r] + dlt) * iv + cGW * P.a0Tf[(size_t)w * kVs + v];
                    ushort_t hi, lo; split_bf(e, hi, lo);
                    P.E0h[o] = hi; P.E0l[o] = lo;
                }
                {
                    float iv = 1.f / (1.f + P.cs[b * kN + v]);
                    float e = cBW * (tB[r][lane] + dlt) * iv + cGW * P.a1Tf[(size_t)w * kVs + v];
                    ushort_t hi, lo; split_bf(e, hi, lo);
                    P.E1h[o] = hi; P.E1l[o] = lo;
                }
            }
        }
        __syncthreads();
    }
}

// ---------------------------------------------------------------------------
extern "C" void kernel_launch(void* const* d_in, const int* in_sizes, int n_in,
                              void* d_out, int out_size, void* d_ws, size_t ws_size,
                              hipStream_t stream) {
    KParams P;
    P.hist = (const float*)d_in[0];
    P.fut  = (const float*)d_in[1];
    P.adj0 = (const float*)d_in[2];
    P.adj1 = (const float*)d_in[3];
    P.emb1 = (const float*)d_in[4];
    P.emb2 = (const float*)d_in[5];
    P.hw1  = (const float*)d_in[6];
    P.hb1  = (const float*)d_in[7];
    P.hw2  = (const float*)d_in[8];
    P.hb2  = (const float*)d_in[9];
    P.hw3  = (const float*)d_in[10];
    P.hb3  = (const float*)d_in[11];
    P.rnw  = (const float*)d_in[12];
    P.rnb  = (const float*)d_in[13];
    P.fcw  = (const float*)d_in[14];
    P.fcb  = (const float*)d_in[15];
    P.out  = (float*)d_out;

    float* ws = (float*)d_ws;
    const size_t SEG = (size_t)66 * kPc;
    size_t off = 0;
    P.xH   = ws + off; off += SEG;
    P.tmp  = ws + off; off += SEG;
    // hop activation hi/lo pairs (8 x 66*kPc ushorts = 4 SEG floats total)
    P.h1Ah = (ushort_t*)(ws + off); off += SEG / 2;
    P.h1Al = (ushort_t*)(ws + off); off += SEG / 2;
    P.h1Bh = (ushort_t*)(ws + off); off += SEG / 2;
    P.h1Bl = (ushort_t*)(ws + off); off += SEG / 2;
    P.h2Ah = (ushort_t*)(ws + off); off += SEG / 2;
    P.h2Al = (ushort_t*)(ws + off); off += SEG / 2;
    P.h2Bh = (ushort_t*)(ws + off); off += SEG / 2;
    P.h2Bl = (ushort_t*)(ws + off); off += SEG / 2;
    P.zbuf = ws + off; off += (size_t)64 * kPc;
    P.e1T  = ws + off; off += kND * kN;
    P.e2T  = ws + off; off += kND * kN;
    P.rs   = ws + off; off += kB * kN;
    P.cs   = ws + off; off += kB * kN;
    P.adjv = ws + off; off += (size_t)kB * kNN2;
    P.a0Tf = ws + off; off += kETb;
    P.a1Tf = ws + off; off += kETb;
    P.rnwC = ws + off; off += (size_t)12 * kDIN * kHID;
    P.hw1C = ws + off; off += (size_t)8 * kDIN * 16;
    P.E0h  = (ushort_t*)(ws + off); off += (size_t)kB * kETb / 2;
    P.E0l  = (ushort_t*)(ws + off); off += (size_t)kB * kETb / 2;
    P.E1h  = (ushort_t*)(ws + off); off += (size_t)kB * kETb / 2;
    P.E1l  = (ushort_t*)(ws + off); off += (size_t)kB * kETb / 2;
    P.a0h  = (ushort_t*)(ws + off); off += kETb / 2;
    P.a0l  = (ushort_t*)(ws + off); off += kETb / 2;
    P.a1h  = (ushort_t*)(ws + off); off += kETb / 2;
    P.a1l  = (ushort_t*)(ws + off); off += kETb / 2;
    P.a0Nh = (ushort_t*)(ws + off); off += kETb / 2;
    P.a0Nl = (ushort_t*)(ws + off); off += kETb / 2;
    P.a1Nh = (ushort_t*)(ws + off); off += kETb / 2;
    P.a1Nl = (ushort_t*)(ws + off); off += kETb / 2;
    P.a0sh = (ushort_t*)(ws + off); off += kETb / 2;
    P.a0sl = (ushort_t*)(ws + off); off += kETb / 2;
    P.a1sh = (ushort_t*)(ws + off); off += kETb / 2;
    P.a1sl = (ushort_t*)(ws + off); off += kETb / 2;
    P.Wgh  = (ushort_t*)(ws + off); off += kWgN / 2;
    P.Wgl  = (ushort_t*)(ws + off); off += kWgN / 2;
    P.Wfh  = (ushort_t*)(ws + off); off += kWfN / 2;
    P.Wfl  = (ushort_t*)(ws + off); off += kWfN / 2;
    P.nv1h = (ushort_t*)(ws + off); off += (size_t)kPc * 64 / 2;
    P.nv1l = (ushort_t*)(ws + off); off += (size_t)kPc * 64 / 2;
    P.nv2h = (ushort_t*)(ws + off); off += (size_t)kPc * 64 / 2;
    P.nv2l = (ushort_t*)(ws + off); off += (size_t)kPc * 64 / 2;

    g_init<<<dim3(1024), dim3(kT), 0, stream>>>(P);
    g_init2<<<dim3(704), dim3(kT), 0, stream>>>(P);
    g_esq<<<dim3(24, 22, 2), dim3(64), 0, stream>>>(P);

    for (int step = 0; step < 24; ++step) {
        const int dec = step >= 12;
        const int t = dec ? step - 12 : step;
        const int hy0 = dec ? 4 : 0;
        const int rb = dec ? 6 : 0;
        const int nextmode = dec ? 2 : (step == 11 ? 1 : 0);

        g_hyper<<<dim3(6, 128), dim3(320), 0, stream>>>(P);
        g_mlp<<<dim3(kPc / 64), dim3(768), 0, stream>>>(P, hy0);
        g_adjm<<<dim3(kPairs, kB), dim3(64), 0, stream>>>(P);
        g_buildE<<<dim3(kBldEV), dim3(kT), 0, stream>>>(P);

        // z/r diffusion
        g_hop1<<<dim3(6, 64), dim3(320), 0, stream>>>(P, P.xH);
        g_hop2<<<dim3(6, 64), dim3(320), 0, stream>>>(P);
        g_gatesm<<<dim3(kPc / 32), dim3(512), 0, stream>>>(P, dec, rb);

        // candidate diffusion
        g_hop1<<<dim3(6, 64), dim3(320), 0, stream>>>(P, P.tmp);
        g_hop2<<<dim3(6, 64), dim3(320), 0, stream>>>(P);
        g_finalm<<<dim3(kPc / 32), dim3(256), 0, stream>>>(P, dec, rb, t, nextmode);
    }
    (void)in_sizes; (void)n_in; (void)out_size; (void)ws_size;
}

// Round 18
// 7135.484 us; speedup vs baseline: 1.1446x; 1.1446x over previous
//
#include <hip/hip_runtime.h>

typedef unsigned short ushort_t;

// ---- problem constants ----
constexpr int kB   = 32;
constexpr int kL   = 12;
constexpr int kN   = 325;
constexpr int kNP  = 328;          // padded node count
constexpr int kPc  = kB * kNP;     // 10496 column stride, channel-major
constexpr int kHID = 64;
constexpr int kDIN = 198;          // 3 * 66
constexpr int kND  = 40;
constexpr int kNN2 = kN * kN;
constexpr float cAW = 0.05f, cBW = 0.95f, cGW = 0.95f, cTA = 3.0f;

constexpr int kT = 192;            // threads for generic kernels (3 waves)
constexpr int kWs = 384;           // transposed-E w rows (6 strips x 64)
constexpr int kVs = 352;           // transposed-E v stride (11*32, padded)
constexpr int kETb = kWs * kVs;    // per-b elements = 135168

constexpr int kBldEV  = 1152;      // 6 wblk * 6 vblk * 32 b
constexpr int kPairs  = 231;       // 21*22/2 unordered 16-tile pairs

// combined-gate MFMA weights: K padded to 352 (= 66 + 4*66 = 330 real)
constexpr int kKg  = 352;
constexpr int kWgN = 2 * 128 * kKg;   // enc/dec x (z,r) x K
constexpr int kWfN = 2 * 64 * kKg;    // enc/dec x Cn x K

// init index-space regions
constexpr int kInit1 = 66 * kPc;                    // xH
constexpr int kInit2 = 2 * kND * kN;                // e1T/e2T
constexpr int kInit3 = 2 * kETb;                    // a0T/a1T hi/lo/f (transposed)
constexpr int kInit4 = 4 * kB * kETb / 2;           // zero E block as uints
constexpr int kInit5 = 12 * kDIN * kHID;            // rnwC combos
constexpr int kInit6 = 8 * kDIN * 16;               // hw1C combos
constexpr int kInit7 = 2 * kETb;                    // a0N/a1N (normal orientation)
constexpr int kInit8 = 4 * kPc * 64 / 2;            // zero nv hi/lo block as uints
constexpr int kInitT = kInit1 + kInit2 + kInit3 + kInit4 + kInit5 + kInit6 + kInit7 + kInit8;

using short8 = __attribute__((ext_vector_type(8))) short;
using f32x4  = __attribute__((ext_vector_type(4))) float;
union ABu { ushort_t u[8]; short8 v; };

__device__ __forceinline__ float sigm_f(float x) { return 1.f / (1.f + __expf(-x)); }
__device__ __forceinline__ float tanh_f(float x) { return 1.f - 2.f / (1.f + __expf(2.f * x)); }
__device__ __forceinline__ ushort_t f2b(float x) {   // fp32 -> bf16 RNE
    union { float f; unsigned u; } c; c.f = x;
    unsigned r = c.u + 0x7FFFu + ((c.u >> 16) & 1u);
    return (ushort_t)(r >> 16);
}
__device__ __forceinline__ float b2f(ushort_t h) {
    union { unsigned u; float f; } c; c.u = ((unsigned)h) << 16; return c.f;
}
__device__ __forceinline__ void split_bf(float x, ushort_t& hi, ushort_t& lo) {
    hi = f2b(x);
    lo = f2b(x - b2f(hi));
}

struct KParams {
    const float *hist, *fut, *adj0, *adj1, *emb1, *emb2;
    const float *hw1, *hb1, *hw2, *hb2, *hw3, *hb3, *rnw, *rnb, *fcw, *fcb;
    float* out;
    float *xH, *hA1, *hB1, *hA2, *hB2, *tmp;              // 6 SEG h-buffers
    float *zbuf, *e1T, *e2T, *rs, *cs, *adjv;
    float *a0Tf, *a1Tf;                                   // fp32 transposed adj [w][v]
    float *rnwC, *hw1C;                                   // combined weights
    ushort_t *E0h, *E0l, *E1h, *E1l;                      // bf16 hi/lo E^T [b][w][v]
    ushort_t *a0h, *a0l, *a1h, *a1l;                      // bf16 hi/lo adj^T [w][v]
    ushort_t *a0Nh, *a0Nl, *a1Nh, *a1Nl;                  // bf16 hi/lo adj (normal) [v][u]
    ushort_t *a0sh, *a0sl, *a1sh, *a1sl;                  // bf16 hi/lo (adj^2)^T [w][v]
    ushort_t *Wgh, *Wgl, *Wfh, *Wfl;                      // gate/final MFMA weights
    ushort_t *nv1h, *nv1l, *nv2h, *nv2l;                  // bf16 hi/lo nv [p][64]
};

// ---------------------------------------------------------------------------
__device__ __forceinline__ void d_init(const KParams& P, int i) {
    if (i < kInit1) {
        int c = i / kPc, p = i - c * kPc;
        int b = p / kNP, n = p - b * kNP;
        if (n < kN) {
            float v = (c < 2) ? P.hist[((b * kL) * kN + n) * 2 + c] : 0.f;
            P.xH[(size_t)c * kPc + p] = v;
        }
        return;
    }
    int j = i - kInit1;
    if (j < kND * kN) { int d = j / kN, n = j - d * kN; P.e1T[j] = P.emb1[n * kND + d]; return; }
    j -= kND * kN;
    if (j < kND * kN) { int d = j / kN, n = j - d * kN; P.e2T[j] = P.emb2[n * kND + d]; return; }
    j -= kND * kN;
    if (j < kInit3) {   // transposed copies: aT[w][v] = adj[v][w]
        int m = j / kETb, idx = j - m * kETb;
        int w = idx / kVs, v = idx - w * kVs;
        const float* adj = m ? P.adj1 : P.adj0;
        float val = (w < kN && v < kN) ? adj[(size_t)v * kN + w] : 0.f;
        ushort_t hi, lo; split_bf(val, hi, lo);
        if (m) { P.a1h[idx] = hi; P.a1l[idx] = lo; P.a1Tf[idx] = val; }
        else   { P.a0h[idx] = hi; P.a0l[idx] = lo; P.a0Tf[idx] = val; }
        return;
    }
    j -= kInit3;
    if (j < kInit4) { ((unsigned*)P.E0h)[j] = 0; return; }   // E0h..E1l contiguous
    j -= kInit4;
    if (j < kInit5) {
        int m = j / (kDIN * kHID), rem = j - m * (kDIN * kHID);
        int k = rem / kHID, o = rem - k * kHID;
        const float* W = P.rnw + (size_t)m * (kDIN * kHID) + o;
        float v;
        if (k < 66)        v = W[(size_t)k * kHID] + cAW * (W[(size_t)(k + 66) * kHID] + W[(size_t)(k + 132) * kHID]);
        else if (k < 132)  v = W[(size_t)k * kHID] + cAW * W[(size_t)(k + 66) * kHID];
        else               v = W[(size_t)k * kHID];
        P.rnwC[j] = v;
        return;
    }
    j -= kInit5;
    if (j < kInit6) {
        int m = j / (kDIN * 16), rem = j - m * (kDIN * 16);
        int k = rem / 16, o = rem - k * 16;
        const float* W = P.hw1 + (size_t)m * (kDIN * 16) + o;
        float v;
        if (k < 66)        v = W[(size_t)k * 16] + cAW * (W[(size_t)(k + 66) * 16] + W[(size_t)(k + 132) * 16]);
        else if (k < 132)  v = cGW * (W[(size_t)k * 16] + cAW * W[(size_t)(k + 66) * 16]);
        else               v = cGW * cGW * W[(size_t)k * 16];
        P.hw1C[j] = v;
        return;
    }
    j -= kInit6;
    if (j < kInit7) {   // normal-orientation copies: aN[v][u] = adj[v][u]
        int m = j / kETb, idx = j - m * kETb;
        int v = idx / kVs, u = idx - v * kVs;
        const float* adj = m ? P.adj1 : P.adj0;
        float val = (v < kN && u < kN) ? adj[(size_t)v * kN + u] : 0.f;
        ushort_t hi, lo; split_bf(val, hi, lo);
        if (m) { P.a1Nh[idx] = hi; P.a1Nl[idx] = lo; }
        else   { P.a0Nh[idx] = hi; P.a0Nl[idx] = lo; }
        return;
    }
    j -= kInit7;
    if (j < kInit8) ((unsigned*)P.nv1h)[j] = 0;   // nv1h..nv2l contiguous
}
__global__ __launch_bounds__(kT) void g_init(KParams P) {
    const int gtid = blockIdx.x * kT + threadIdx.x;
    const int nt = gridDim.x * kT;
    for (int i = gtid; i < kInitT; i += nt) d_init(P, i);
}

// ---------------------------------------------------------------------------
// g_init2: build gate/final MFMA weight fragments from rnwC.
__global__ __launch_bounds__(kT) void g_init2(KParams P) {
    const int tot = kWgN + kWfN;
    for (int i = blockIdx.x * kT + threadIdx.x; i < tot; i += gridDim.x * kT) {
        bool isG = i < kWgN;
        int j = isG ? i : i - kWgN;
        int Mloc = isG ? 128 : 64;
        int g = j / (Mloc * kKg);
        int rem = j - g * (Mloc * kKg);
        int m = rem / kKg, k = rem - m * kKg;
        int rbg = g ? 6 : 0;
        int base0, base1, h;
        if (isG) {
            if (m < 64) { base0 = rbg + 0; base1 = rbg + 1; h = m; }
            else        { base0 = rbg + 2; base1 = rbg + 3; h = m - 64; }
        } else { base0 = rbg + 4; base1 = rbg + 5; h = m; }
        float w = 0.f;
        if (k < 66)
            w = P.rnwC[(size_t)base0 * (kDIN * kHID) + k * kHID + h]
              + P.rnwC[(size_t)base1 * (kDIN * kHID) + k * kHID + h];
        else if (k < 198)
            w = P.rnwC[(size_t)base0 * (kDIN * kHID) + k * kHID + h];
        else if (k < 330)
            w = P.rnwC[(size_t)base1 * (kDIN * kHID) + (k - 132) * kHID + h];
        ushort_t hi, lo; split_bf(w, hi, lo);
        if (isG) { P.Wgh[j] = hi; P.Wgl[j] = lo; }
        else     { P.Wfh[j] = hi; P.Wfl[j] = lo; }
    }
}

// ---------------------------------------------------------------------------
// g_esq: (adj^2)^T = aT * aN (split-bf16 3-mfma).  Once per call.
__global__ __launch_bounds__(64) void g_esq(KParams P) {
    const int lane = threadIdx.x;
    const int quad = lane >> 4, ln15 = lane & 15;
    const int m0 = blockIdx.x * 16, n0 = blockIdx.y * 16;
    const int mat = blockIdx.z;
    const ushort_t* STh = mat ? P.a1h : P.a0h;
    const ushort_t* STl = mat ? P.a1l : P.a0l;
    const ushort_t* SNh = mat ? P.a1Nh : P.a0Nh;
    const ushort_t* SNl = mat ? P.a1Nl : P.a0Nl;
    ushort_t* Oh = mat ? P.a1sh : P.a0sh;
    ushort_t* Ol = mat ? P.a1sl : P.a0sl;
    const size_t arow = (size_t)(m0 + ln15) * kVs + quad * 8;
    const size_t browq = (size_t)(n0 + ln15) * kVs + quad * 8;
    f32x4 acc = f32x4{0.f, 0.f, 0.f, 0.f};
    for (int ks = 0; ks < 11; ++ks) {
        const int u0 = ks * 32;
        ABu ah, al, bh, bl;
        ah.v = *(const short8*)(STh + arow + u0);
        al.v = *(const short8*)(STl + arow + u0);
        bh.v = *(const short8*)(SNh + browq + u0);
        bl.v = *(const short8*)(SNl + browq + u0);
        acc = __builtin_amdgcn_mfma_f32_16x16x32_bf16(ah.v, bh.v, acc, 0, 0, 0);
        acc = __builtin_amdgcn_mfma_f32_16x16x32_bf16(al.v, bh.v, acc, 0, 0, 0);
        acc = __builtin_amdgcn_mfma_f32_16x16x32_bf16(ah.v, bl.v, acc, 0, 0, 0);
    }
#pragma unroll
    for (int r = 0; r < 4; ++r) {
        size_t o = (size_t)(m0 + quad * 4 + r) * kVs + n0 + ln15;
        ushort_t hi, lo; split_bf(acc[r], hi, lo);
        Oh[o] = hi; Ol[o] = lo;
    }
}

// ---------------------------------------------------------------------------
// shared MFMA hop tile: acc[nn] += sum_v M[v,w]*h[c,v] (split-bf16, 3 mfma)
__device__ __forceinline__ void hop_tile(
        const ushort_t* __restrict__ EH, const ushort_t* __restrict__ EL,
        const float* __restrict__ ap, const size_t* brow, f32x4* acc) {
    for (int ks = 0; ks < 11; ++ks) {
        const int v0 = ks * 32;
        float4 f0 = *(const float4*)(ap + v0);
        float4 f1 = *(const float4*)(ap + v0 + 4);
        float fs[8] = {f0.x, f0.y, f0.z, f0.w, f1.x, f1.y, f1.z, f1.w};
        ABu ah, al;
#pragma unroll
        for (int j = 0; j < 8; ++j) {
            ushort_t hi = f2b(fs[j]);
            ah.u[j] = hi;
            al.u[j] = f2b(fs[j] - b2f(hi));
        }
#pragma unroll
        for (int nn = 0; nn < 4; ++nn) {
            short8 bh = *(const short8*)(EH + brow[nn] + v0);
            short8 bl = *(const short8*)(EL + brow[nn] + v0);
            acc[nn] = __builtin_amdgcn_mfma_f32_16x16x32_bf16(ah.v, bh, acc[nn], 0, 0, 0);
            acc[nn] = __builtin_amdgcn_mfma_f32_16x16x32_bf16(al.v, bh, acc[nn], 0, 0, 0);
            acc[nn] = __builtin_amdgcn_mfma_f32_16x16x32_bf16(ah.v, bl, acc[nn], 0, 0, 0);
        }
    }
}

// ---------------------------------------------------------------------------
// g_hyper: both hyper hops in one launch (A and precomputed A^2, static).
__global__ __launch_bounds__(320) void g_hyper(KParams P) {
    const int lane = threadIdx.x & 63;
    const int ct = threadIdx.x >> 6;
    const int quad = lane >> 4, ln15 = lane & 15;
    const int w0 = blockIdx.x * 64;
    const int zb = blockIdx.y;
    const int hop = zb >> 6;
    const int z = zb & 63;
    const int sel = z >> 5, b = z & 31;
    const ushort_t* EH = hop ? (sel ? P.a1sh : P.a0sh) : (sel ? P.a1h : P.a0h);
    const ushort_t* EL = hop ? (sel ? P.a1sl : P.a0sl) : (sel ? P.a1l : P.a0l);
    float* ob = (hop ? (sel ? P.hB2 : P.hA2) : (sel ? P.hB1 : P.hA1)) + b * kNP;
    const float* ap = P.xH + b * kNP + (size_t)(ct * 16 + ln15) * kPc + quad * 8;
    size_t brow[4];
#pragma unroll
    for (int nn = 0; nn < 4; ++nn)
        brow[nn] = (size_t)(w0 + nn * 16 + ln15) * kVs + quad * 8;
    f32x4 acc[4];
#pragma unroll
    for (int nn = 0; nn < 4; ++nn) acc[nn] = f32x4{0.f, 0.f, 0.f, 0.f};
    hop_tile(EH, EL, ap, brow, acc);
#pragma unroll
    for (int nn = 0; nn < 4; ++nn) {
        int w = w0 + nn * 16 + ln15;
        if (w < kN) {
#pragma unroll
            for (int r = 0; r < 4; ++r) {
                int c = ct * 16 + quad * 4 + r;
                if (c < 66) ob[(size_t)c * kPc + w] = acc[nn][r];
            }
        }
    }
}

// ---------------------------------------------------------------------------
// g_hopm: generic split-bf16 MFMA diffusion hop (R10-proven).
__global__ __launch_bounds__(320) void g_hopm(
        const ushort_t* __restrict__ MaH, const ushort_t* __restrict__ MaL,
        const ushort_t* __restrict__ MbH, const ushort_t* __restrict__ MbL,
        int mstride,
        const float* __restrict__ hA, const float* __restrict__ hB,
        float* __restrict__ oA, float* __restrict__ oB) {
    const int lane = threadIdx.x & 63;
    const int ct = threadIdx.x >> 6;
    const int quad = lane >> 4, ln15 = lane & 15;
    const int w0 = blockIdx.x * 64;
    const int zb = blockIdx.y;
    const int sel = zb >> 5, b = zb & 31;
    const ushort_t* EH = (sel ? MbH : MaH) + (size_t)b * mstride;
    const ushort_t* EL = (sel ? MbL : MaL) + (size_t)b * mstride;
    const float* hb = (sel ? hB : hA) + b * kNP;
    float* ob = (sel ? oB : oA) + b * kNP;
    const float* ap = hb + (size_t)(ct * 16 + ln15) * kPc + quad * 8;
    size_t brow[4];
#pragma unroll
    for (int nn = 0; nn < 4; ++nn)
        brow[nn] = (size_t)(w0 + nn * 16 + ln15) * kVs + quad * 8;
    f32x4 acc[4];
#pragma unroll
    for (int nn = 0; nn < 4; ++nn) acc[nn] = f32x4{0.f, 0.f, 0.f, 0.f};
    hop_tile(EH, EL, ap, brow, acc);
#pragma unroll
    for (int nn = 0; nn < 4; ++nn) {
        int w = w0 + nn * 16 + ln15;
        if (w < kN) {
#pragma unroll
            for (int r = 0; r < 4; ++r) {
                int c = ct * 16 + quad * 4 + r;
                if (c < 66) ob[(size_t)c * kPc + w] = acc[nn][r];
            }
        }
    }
}

// ---------------------------------------------------------------------------
// g_gatesm: MFMA gates GEMM (R13-proven).
__global__ __launch_bounds__(512) void g_gatesm(KParams P, int g, int rb) {
    __shared__ ushort_t Bh[2][32][40];
    __shared__ ushort_t Bl[2][32][40];
    const int t = threadIdx.x;
    const int lane = t & 63;
    const int wv = t >> 6;
    const int quad = lane >> 4, ln15 = lane & 15;
    const int p0 = blockIdx.x * 32;
    const float* segp[5] = {P.xH, P.hA1, P.hA2, P.hB1, P.hB2};
    const int m = wv * 16 + ln15;
    const ushort_t* Ah = P.Wgh + ((size_t)(g * 128 + m)) * kKg + quad * 8;
    const ushort_t* Al = P.Wgl + ((size_t)(g * 128 + m)) * kKg + quad * 8;

    f32x4 acc[2];
    acc[0] = f32x4{0.f, 0.f, 0.f, 0.f};
    acc[1] = f32x4{0.f, 0.f, 0.f, 0.f};

    auto stage = [&](int bi, int ks) {
#pragma unroll
        for (int e = 0; e < 2; ++e) {
            int idx = e * 512 + t;
            int k = idx >> 5, n = idx & 31;
            int kg = ks * 32 + k;
            float v = 0.f;
            if (kg < 330) {
                int seg = kg / 66, row = kg - seg * 66;
                v = segp[seg][(size_t)row * kPc + p0 + n];
            }
            ushort_t hi, lo; split_bf(v, hi, lo);
            Bh[bi][n][k] = hi; Bl[bi][n][k] = lo;
        }
    };
    stage(0, 0);
    __syncthreads();
    for (int ks = 0; ks < 11; ++ks) {
        const int bi = ks & 1;
        ABu ah, al;
        ah.v = *(const short8*)(Ah + ks * 32);
        al.v = *(const short8*)(Al + ks * 32);
#pragma unroll
        for (int nt = 0; nt < 2; ++nt) {
            ABu bh, bl;
            bh.v = *(const short8*)&Bh[bi][nt * 16 + ln15][quad * 8];
            bl.v = *(const short8*)&Bl[bi][nt * 16 + ln15][quad * 8];
            acc[nt] = __builtin_amdgcn_mfma_f32_16x16x32_bf16(ah.v, bh.v, acc[nt], 0, 0, 0);
            acc[nt] = __builtin_amdgcn_mfma_f32_16x16x32_bf16(al.v, bh.v, acc[nt], 0, 0, 0);
            acc[nt] = __builtin_amdgcn_mfma_f32_16x16x32_bf16(ah.v, bl.v, acc[nt], 0, 0, 0);
        }
        if (ks + 1 < 11) stage((ks + 1) & 1, ks + 1);
        __syncthreads();
    }
#pragma unroll
    for (int nt = 0; nt < 2; ++nt) {
        int p = p0 + nt * 16 + ln15;
#pragma unroll
        for (int r = 0; r < 4; ++r) {
            int mm = wv * 16 + quad * 4 + r;
            float v = acc[nt][r];
            if (mm < 64) {
                int h = mm;
                float bz = P.rnb[(rb + 0) * kHID + h] + P.rnb[(rb + 1) * kHID + h];
                P.zbuf[(size_t)h * kPc + p] = sigm_f(v + bz);
            } else {
                int h = mm - 64;
                float br = P.rnb[(rb + 2) * kHID + h] + P.rnb[(rb + 3) * kHID + h];
                float rr = sigm_f(v + br);
                P.tmp[(size_t)(2 + h) * kPc + p] = rr * P.xH[(size_t)(2 + h) * kPc + p];
            }
        }
    }
    if (wv == 0 && quad == 0) {
#pragma unroll
        for (int nt = 0; nt < 2; ++nt) {
            int p = p0 + nt * 16 + ln15;
            P.tmp[p] = P.xH[p];
            P.tmp[kPc + p] = P.xH[kPc + p];
        }
    }
}

// ---------------------------------------------------------------------------
// g_finalm: MFMA Cn GEMM + GRU update + next-step x rows + folded decoder out.
__global__ __launch_bounds__(256) void g_finalm(KParams P, int g, int rb, int t_, int nextmode) {
    __shared__ ushort_t Bh[2][32][40];
    __shared__ ushort_t Bl[2][32][40];
    __shared__ float sred[16][33];
    const int t = threadIdx.x;
    const int lane = t & 63;
    const int wv = t >> 6;
    const int quad = lane >> 4, ln15 = lane & 15;
    const int p0 = blockIdx.x * 32;
    const float* segp[5] = {P.tmp, P.hA1, P.hA2, P.hB1, P.hB2};
    const int m = wv * 16 + ln15;
    const ushort_t* Ah = P.Wfh + ((size_t)(g * 64 + m)) * kKg + quad * 8;
    const ushort_t* Al = P.Wfl + ((size_t)(g * 64 + m)) * kKg + quad * 8;

    f32x4 acc[2];
    acc[0] = f32x4{0.f, 0.f, 0.f, 0.f};
    acc[1] = f32x4{0.f, 0.f, 0.f, 0.f};

    auto stage = [&](int bi, int ks) {
#pragma unroll
        for (int e = 0; e < 4; ++e) {
            int idx = e * 256 + t;
            int k = idx >> 5, n = idx & 31;
            int kg = ks * 32 + k;
            float v = 0.f;
            if (kg < 330) {
                int seg = kg / 66, row = kg - seg * 66;
                v = segp[seg][(size_t)row * kPc + p0 + n];
            }
            ushort_t hi, lo; split_bf(v, hi, lo);
            Bh[bi][n][k] = hi; Bl[bi][n][k] = lo;
        }
    };
    stage(0, 0);
    __syncthreads();
    for (int ks = 0; ks < 11; ++ks) {
        const int bi = ks & 1;
        ABu ah, al;
        ah.v = *(const short8*)(Ah + ks * 32);
        al.v = *(const short8*)(Al + ks * 32);
#pragma unroll
        for (int nt = 0; nt < 2; ++nt) {
            ABu bh, bl;
            bh.v = *(const short8*)&Bh[bi][nt * 16 + ln15][quad * 8];
            bl.v = *(const short8*)&Bl[bi][nt * 16 + ln15][quad * 8];
            acc[nt] = __builtin_amdgcn_mfma_f32_16x16x32_bf16(ah.v, bh.v, acc[nt], 0, 0, 0);
            acc[nt] = __builtin_amdgcn_mfma_f32_16x16x32_bf16(al.v, bh.v, acc[nt], 0, 0, 0);
            acc[nt] = __builtin_amdgcn_mfma_f32_16x16x32_bf16(ah.v, bl.v, acc[nt], 0, 0, 0);
        }
        if (ks + 1 < 11) stage((ks + 1) & 1, ks + 1);
        __syncthreads();
    }
    float pout[2] = {0.f, 0.f};
#pragma unroll
    for (int nt = 0; nt < 2; ++nt) {
        int p = p0 + nt * 16 + ln15;
#pragma unroll
        for (int r = 0; r < 4; ++r) {
            int h = wv * 16 + quad * 4 + r;
            float bc = P.rnb[(rb + 4) * kHID + h] + P.rnb[(rb + 5) * kHID + h];
            float cn = tanh_f(acc[nt][r] + bc);
            float zz = P.zbuf[(size_t)h * kPc + p];
            size_t hidx = (size_t)(2 + h) * kPc + p;
            float hv = P.xH[hidx];
            float hn = zz * hv + (1.f - zz) * cn;
            P.xH[hidx] = hn;
            pout[nt] = fmaf(P.fcw[h], hn, pout[nt]);
        }
    }
    if (nextmode != 2) {
        if (wv == 0 && quad == 0) {
#pragma unroll
            for (int nt = 0; nt < 2; ++nt) {
                int p = p0 + nt * 16 + ln15;
                int b = p / kNP, n = p - b * kNP;
                if (n < kN) {
                    float r0, r1;
                    if (nextmode == 0) {
                        r0 = P.hist[((b * kL + (t_ + 1)) * kN + n) * 2 + 0];
                        r1 = P.hist[((b * kL + (t_ + 1)) * kN + n) * 2 + 1];
                    } else {
                        r0 = 0.f;
                        r1 = P.fut[((b * kL + 0) * kN + n) * 2 + 1];
                    }
                    P.xH[p] = r0;
                    P.xH[kPc + p] = r1;
                }
            }
        }
    } else {
        // decoder: out = Hnew . fcw + fcb ; feedback next x rows
#pragma unroll
        for (int nt = 0; nt < 2; ++nt)
            sred[wv * 4 + quad][nt * 16 + ln15] = pout[nt];
        __syncthreads();
        if (t < 32) {
            int col = t;
            float s = P.fcb[0];
#pragma unroll
            for (int q = 0; q < 16; ++q) s += sred[q][col];
            int p = p0 + col;
            int b = p / kNP, n = p - b * kNP;
            if (n < kN) {
                P.out[(b * 12 + t_) * kN + n] = s;
                if (t_ + 1 < 12) {
                    P.xH[p] = s;
                    P.xH[kPc + p] = P.fut[((b * kL + (t_ + 1)) * kN + n) * 2 + 1];
                }
            }
        }
    }
}

// ---------------------------------------------------------------------------
// fused hyper MLP (combined hw1C), epilogue writes nv as hi/lo bf16 [p][64]
__global__ __launch_bounds__(768) void g_mlp(KParams P, int hy0) {
    {
        int zt = blockIdx.x * 768 + threadIdx.x;
        if (zt < kB * kN) P.rs[zt] = 0.f;
        else if (zt < 2 * kB * kN) P.cs[zt - kB * kN] = 0.f;
    }
    __shared__ float part[12][16][64];
    __shared__ float s2s[4][2][64];
    const int lane = threadIdx.x & 63;
    const int wv = threadIdx.x >> 6;
    const int p = blockIdx.x * 64 + lane;
    const int m = wv & 3, s = wv >> 2;
    const int ig = hy0 + m;
    const float* src = (s == 0) ? P.xH : (s == 1) ? ((m & 1) ? P.hB1 : P.hA1)
                                                  : ((m & 1) ? P.hB2 : P.hA2);
    const float* wp = P.hw1C + (size_t)ig * (kDIN * 16);
    float acc[16];
#pragma unroll
    for (int o = 0; o < 16; ++o) acc[o] = 0.f;
#pragma unroll 2
    for (int kl = 0; kl < 66; ++kl) {
        int kk = s * 66 + kl;
        float u = src[(size_t)kl * kPc + p];
        float4 wa = *(const float4*)(wp + kk * 16);
        float4 wb = *(const float4*)(wp + kk * 16 + 4);
        float4 wc = *(const float4*)(wp + kk * 16 + 8);
        float4 wd = *(const float4*)(wp + kk * 16 + 12);
        acc[0]  = fmaf(u, wa.x, acc[0]);  acc[1]  = fmaf(u, wa.y, acc[1]);
        acc[2]  = fmaf(u, wa.z, acc[2]);  acc[3]  = fmaf(u, wa.w, acc[3]);
        acc[4]  = fmaf(u, wb.x, acc[4]);  acc[5]  = fmaf(u, wb.y, acc[5]);
        acc[6]  = fmaf(u, wb.z, acc[6]);  acc[7]  = fmaf(u, wb.w, acc[7]);
        acc[8]  = fmaf(u, wc.x, acc[8]);  acc[9]  = fmaf(u, wc.y, acc[9]);
        acc[10] = fmaf(u, wc.z, acc[10]); acc[11] = fmaf(u, wc.w, acc[11]);
        acc[12] = fmaf(u, wd.x, acc[12]); acc[13] = fmaf(u, wd.y, acc[13]);
        acc[14] = fmaf(u, wd.z, acc[14]); acc[15] = fmaf(u, wd.w, acc[15]);
    }
#pragma unroll
    for (int o = 0; o < 16; ++o) part[wv][o][lane] = acc[o];
    __syncthreads();
    if (wv < 4) {
        int mm = wv, igm = hy0 + mm;
        float sv[16];
#pragma unroll
        for (int o = 0; o < 16; ++o)
            sv[o] = sigm_f(P.hb1[igm * 16 + o] + part[mm][o][lane] + part[4 + mm][o][lane] + part[8 + mm][o][lane]);
#pragma unroll
        for (int j = 0; j < 2; ++j) {
            float t = P.hb2[igm * 2 + j];
#pragma unroll
            for (int o = 0; o < 16; ++o) t = fmaf(sv[o], P.hw2[igm * 32 + o * 2 + j], t);
            s2s[mm][j][lane] = sigm_f(t);
        }
    }
    __syncthreads();
    int b = p / kNP, n = p - b * kNP;
    int nc = (n < kN) ? n : (kN - 1);
    bool ok = (n < kN);
    if (wv < 2) {
        int i0 = hy0 + wv * 2;
        float sa0 = s2s[wv * 2 + 0][0][lane], sa1 = s2s[wv * 2 + 0][1][lane];
        float sb0 = s2s[wv * 2 + 1][0][lane], sb1 = s2s[wv * 2 + 1][1][lane];
        const float* eT = wv ? P.e2T : P.e1T;
        ushort_t* nvh = wv ? P.nv2h : P.nv1h;
        ushort_t* nvl = wv ? P.nv2l : P.nv1l;
#pragma unroll 4
        for (int d = 0; d < kND; ++d) {
            float f = P.hb3[(i0 + 0) * kND + d] + P.hb3[(i0 + 1) * kND + d]
                    + sa0 * P.hw3[(i0 + 0) * 80 + d] + sa1 * P.hw3[(i0 + 0) * 80 + 40 + d]
                    + sb0 * P.hw3[(i0 + 1) * 80 + d] + sb1 * P.hw3[(i0 + 1) * 80 + 40 + d];
            float r = tanh_f(cTA * eT[d * kN + nc] * f);
            if (ok) {
                ushort_t hi, lo; split_bf(r, hi, lo);
                nvh[(size_t)p * 64 + d] = hi;
                nvl[(size_t)p * 64 + d] = lo;
            }
        }
    }
}

// ---------------------------------------------------------------------------
// g_adjm: MFMA adjacency (R14-proven).
__global__ __launch_bounds__(64) void g_adjm(KParams P) {
    __shared__ float c2t[16][17];
    const int b = blockIdx.y;
    int ti = 0, rem = blockIdx.x;
    while (rem >= 21 - ti) { rem -= 21 - ti; ++ti; }
    const int tj = ti + rem;
    const int i0 = ti * 16, j0 = tj * 16;
    const int lane = threadIdx.x, quad = lane >> 4, ln15 = lane & 15;
    const size_t pb = (size_t)b * kNP;
    auto rowoff = [&](int n) {
        int ncl = (n < kNP) ? n : (kNP - 1);
        return (pb + ncl) * 64 + quad * 8;
    };
    const size_t aI = rowoff(i0 + ln15);
    const size_t aJ = rowoff(j0 + ln15);

    f32x4 c1 = f32x4{0.f, 0.f, 0.f, 0.f};
    f32x4 c2 = f32x4{0.f, 0.f, 0.f, 0.f};
#pragma unroll
    for (int ks = 0; ks < 2; ++ks) {
        const int k0 = ks * 32;
        ABu a1h, a1l, b1h, b1l, a2h, a2l, b2h, b2l;
        a1h.v = *(const short8*)(P.nv1h + aI + k0);
        a1l.v = *(const short8*)(P.nv1l + aI + k0);
        b1h.v = *(const short8*)(P.nv2h + aJ + k0);
        b1l.v = *(const short8*)(P.nv2l + aJ + k0);
        c1 = __builtin_amdgcn_mfma_f32_16x16x32_bf16(a1h.v, b1h.v, c1, 0, 0, 0);
        c1 = __builtin_amdgcn_mfma_f32_16x16x32_bf16(a1l.v, b1h.v, c1, 0, 0, 0);
        c1 = __builtin_amdgcn_mfma_f32_16x16x32_bf16(a1h.v, b1l.v, c1, 0, 0, 0);
        a2h.v = *(const short8*)(P.nv1h + aJ + k0);
        a2l.v = *(const short8*)(P.nv1l + aJ + k0);
        b2h.v = *(const short8*)(P.nv2h + aI + k0);
        b2l.v = *(const short8*)(P.nv2l + aI + k0);
        c2 = __builtin_amdgcn_mfma_f32_16x16x32_bf16(a2h.v, b2h.v, c2, 0, 0, 0);
        c2 = __builtin_amdgcn_mfma_f32_16x16x32_bf16(a2l.v, b2h.v, c2, 0, 0, 0);
        c2 = __builtin_amdgcn_mfma_f32_16x16x32_bf16(a2h.v, b2l.v, c2, 0, 0, 0);
    }
#pragma unroll
    for (int r = 0; r < 4; ++r) c2t[quad * 4 + r][ln15] = c2[r];
    __syncthreads();

    size_t base = (size_t)b * kNN2;
    const bool diag = (ti == tj);
    float v1[4], v2[4];
#pragma unroll
    for (int r = 0; r < 4; ++r) {
        int i = i0 + quad * 4 + r;
        int j = j0 + ln15;
        float aji = c2t[ln15][quad * 4 + r];
        float tv = tanh_f(cTA * (c1[r] - aji));
        bool valid = (i < kN) && (j < kN);
        v1[r] = valid ? fmaxf(tv, 0.f) : 0.f;
        v2[r] = valid ? fmaxf(-tv, 0.f) : 0.f;
        if (valid) {
            P.adjv[base + (size_t)i * kN + j] = v1[r];
            if (!diag) P.adjv[base + (size_t)j * kN + i] = v2[r];
        }
    }
#pragma unroll
    for (int r = 0; r < 4; ++r) {
        float sr = v1[r];
#pragma unroll
        for (int off = 1; off < 16; off <<= 1) sr += __shfl_xor(sr, off);
        int i = i0 + quad * 4 + r;
        if (ln15 == 0 && i < kN) atomicAdd(&P.rs[b * kN + i], sr);
    }
    {
        float pc = v1[0] + v1[1] + v1[2] + v1[3];
        pc += __shfl_xor(pc, 16);
        pc += __shfl_xor(pc, 32);
        int j = j0 + ln15;
        if (quad == 0 && j < kN) atomicAdd(&P.cs[b * kN + j], pc);
    }
    if (!diag) {
        {
            float pr = v2[0] + v2[1] + v2[2] + v2[3];
            pr += __shfl_xor(pr, 16);
            pr += __shfl_xor(pr, 32);
            int j = j0 + ln15;
            if (quad == 0 && j < kN) atomicAdd(&P.rs[b * kN + j], pr);
        }
#pragma unroll
        for (int r = 0; r < 4; ++r) {
            float sc = v2[r];
#pragma unroll
            for (int off = 1; off < 16; off <<= 1) sc += __shfl_xor(sc, off);
            int i = i0 + quad * 4 + r;
            if (ln15 == 0 && i < kN) atomicAdd(&P.cs[b * kN + i], sc);
        }
    }
}

// ---------------------------------------------------------------------------
// buildE: transposed bf16 hi/lo E0/E1 — R14-proven
__global__ __launch_bounds__(kT) void g_buildE(KParams P) {
    __shared__ float tA[64][65];
    __shared__ float tB[64][65];
    for (int vb = blockIdx.x; vb < kBldEV; vb += gridDim.x) {
        const int lane = threadIdx.x & 63;
        const int wv = threadIdx.x >> 6;
        const int w0 = (vb % 6) * 64;
        const int v0 = ((vb / 6) % 6) * 64;
        const int b = vb / 36;
        const float* av = P.adjv + (size_t)b * kNN2;
        for (int r = wv; r < 64; r += 3) {
            int v = v0 + r, w = w0 + lane;
            tA[r][lane] = (v < kN && w < kN) ? av[(size_t)v * kN + w] : 0.f;
            int v2 = w0 + r, w2 = v0 + lane;
            tB[r][lane] = (v2 < kN && w2 < kN) ? av[(size_t)v2 * kN + w2] : 0.f;
        }
        __syncthreads();
        for (int r = wv; r < 64; r += 3) {
            int w = w0 + r;
            int v = v0 + lane;
            if (w < kN && v < kN) {
                size_t o = ((size_t)b * kWs + w) * kVs + v;
                float dlt = (v == w) ? 1.f : 0.f;
                {
                    float iv = 1.f / (1.f + P.rs[b * kN + v]);
                    float e = cBW * (tA[lane][r] + dlt) * iv + cGW * P.a0Tf[(size_t)w * kVs + v];
                    ushort_t hi, lo; split_bf(e, hi, lo);
                    P.E0h[o] = hi; P.E0l[o] = lo;
                }
                {
                    float iv = 1.f / (1.f + P.cs[b * kN + v]);
                    float e = cBW * (tB[r][lane] + dlt) * iv + cGW * P.a1Tf[(size_t)w * kVs + v];
                    ushort_t hi, lo; split_bf(e, hi, lo);
                    P.E1h[o] = hi; P.E1l[o] = lo;
                }
            }
        }
        __syncthreads();
    }
}

// ---------------------------------------------------------------------------
extern "C" void kernel_launch(void* const* d_in, const int* in_sizes, int n_in,
                              void* d_out, int out_size, void* d_ws, size_t ws_size,
                              hipStream_t stream) {
    KParams P;
    P.hist = (const float*)d_in[0];
    P.fut  = (const float*)d_in[1];
    P.adj0 = (const float*)d_in[2];
    P.adj1 = (const float*)d_in[3];
    P.emb1 = (const float*)d_in[4];
    P.emb2 = (const float*)d_in[5];
    P.hw1  = (const float*)d_in[6];
    P.hb1  = (const float*)d_in[7];
    P.hw2  = (const float*)d_in[8];
    P.hb2  = (const float*)d_in[9];
    P.hw3  = (const float*)d_in[10];
    P.hb3  = (const float*)d_in[11];
    P.rnw  = (const float*)d_in[12];
    P.rnb  = (const float*)d_in[13];
    P.fcw  = (const float*)d_in[14];
    P.fcb  = (const float*)d_in[15];
    P.out  = (float*)d_out;

    float* ws = (float*)d_ws;
    const size_t SEG = (size_t)66 * kPc;
    size_t off = 0;
    P.xH   = ws + off; off += SEG;
    P.hA1  = ws + off; off += SEG;
    P.hB1  = ws + off; off += SEG;
    P.hA2  = ws + off; off += SEG;
    P.hB2  = ws + off; off += SEG;
    P.tmp  = ws + off; off += SEG;
    P.zbuf = ws + off; off += (size_t)64 * kPc;
    P.e1T  = ws + off; off += kND * kN;
    P.e2T  = ws + off; off += kND * kN;
    P.rs   = ws + off; off += kB * kN;
    P.cs   = ws + off; off += kB * kN;
    P.adjv = ws + off; off += (size_t)kB * kNN2;
    P.a0Tf = ws + off; off += kETb;
    P.a1Tf = ws + off; off += kETb;
    P.rnwC = ws + off; off += (size_t)12 * kDIN * kHID;
    P.hw1C = ws + off; off += (size_t)8 * kDIN * 16;
    P.E0h  = (ushort_t*)(ws + off); off += (size_t)kB * kETb / 2;
    P.E0l  = (ushort_t*)(ws + off); off += (size_t)kB * kETb / 2;
    P.E1h  = (ushort_t*)(ws + off); off += (size_t)kB * kETb / 2;
    P.E1l  = (ushort_t*)(ws + off); off += (size_t)kB * kETb / 2;
    P.a0h  = (ushort_t*)(ws + off); off += kETb / 2;
    P.a0l  = (ushort_t*)(ws + off); off += kETb / 2;
    P.a1h  = (ushort_t*)(ws + off); off += kETb / 2;
    P.a1l  = (ushort_t*)(ws + off); off += kETb / 2;
    P.a0Nh = (ushort_t*)(ws + off); off += kETb / 2;
    P.a0Nl = (ushort_t*)(ws + off); off += kETb / 2;
    P.a1Nh = (ushort_t*)(ws + off); off += kETb / 2;
    P.a1Nl = (ushort_t*)(ws + off); off += kETb / 2;
    P.a0sh = (ushort_t*)(ws + off); off += kETb / 2;
    P.a0sl = (ushort_t*)(ws + off); off += kETb / 2;
    P.a1sh = (ushort_t*)(ws + off); off += kETb / 2;
    P.a1sl = (ushort_t*)(ws + off); off += kETb / 2;
    P.Wgh  = (ushort_t*)(ws + off); off += kWgN / 2;
    P.Wgl  = (ushort_t*)(ws + off); off += kWgN / 2;
    P.Wfh  = (ushort_t*)(ws + off); off += kWfN / 2;
    P.Wfl  = (ushort_t*)(ws + off); off += kWfN / 2;
    P.nv1h = (ushort_t*)(ws + off); off += (size_t)kPc * 64 / 2;
    P.nv1l = (ushort_t*)(ws + off); off += (size_t)kPc * 64 / 2;
    P.nv2h = (ushort_t*)(ws + off); off += (size_t)kPc * 64 / 2;
    P.nv2l = (ushort_t*)(ws + off); off += (size_t)kPc * 64 / 2;

    g_init<<<dim3(1024), dim3(kT), 0, stream>>>(P);
    g_init2<<<dim3(704), dim3(kT), 0, stream>>>(P);
    g_esq<<<dim3(24, 22, 2), dim3(64), 0, stream>>>(P);

    for (int step = 0; step < 24; ++step) {
        const int dec = step >= 12;
        const int t = dec ? step - 12 : step;
        const int hy0 = dec ? 4 : 0;
        const int rb = dec ? 6 : 0;
        const int nextmode = dec ? 2 : (step == 11 ? 1 : 0);

        g_hyper<<<dim3(6, 128), dim3(320), 0, stream>>>(P);
        g_mlp<<<dim3(kPc / 64), dim3(768), 0, stream>>>(P, hy0);
        g_adjm<<<dim3(kPairs, kB), dim3(64), 0, stream>>>(P);
        g_buildE<<<dim3(kBldEV), dim3(kT), 0, stream>>>(P);

        // z/r diffusion
        g_hopm<<<dim3(6, 64), dim3(320), 0, stream>>>(P.E0h, P.E0l, P.E1h, P.E1l, kETb,
                                                      P.xH, P.xH, P.hA1, P.hB1);
        g_hopm<<<dim3(6, 64), dim3(320), 0, stream>>>(P.E0h, P.E0l, P.E1h, P.E1l, kETb,
                                                      P.hA1, P.hB1, P.hA2, P.hB2);
        g_gatesm<<<dim3(kPc / 32), dim3(512), 0, stream>>>(P, dec, rb);

        // candidate diffusion
        g_hopm<<<dim3(6, 64), dim3(320), 0, stream>>>(P.E0h, P.E0l, P.E1h, P.E1l, kETb,
                                                      P.tmp, P.tmp, P.hA1, P.hB1);
        g_hopm<<<dim3(6, 64), dim3(320), 0, stream>>>(P.E0h, P.E0l, P.E1h, P.E1l, kETb,
                                                      P.hA1, P.hB1, P.hA2, P.hB2);
        g_finalm<<<dim3(kPc / 32), dim3(256), 0, stream>>>(P, dec, rb, t, nextmode);
    }
    (void)in_sizes; (void)n_in; (void)out_size; (void)ws_size;
}